// Round 9
// baseline (173.576 us; speedup 1.0000x reference)
//
#include <hip/hip_runtime.h>

#define B_ 8
#define T_ 2048
#define H_ 256
#define PSTR 40                  // P LDS row stride (elems)
#define SCALE2 0.0901684403f     // (1/16) * log2(e)
#define SLOPE2 0.00563552752f    // 2^-8 * log2(e)
#define NFREQ 0.103810252959f    // log2(10000)/128
#define INV2PI 0.15915494309f

typedef __attribute__((ext_vector_type(8))) short bf16x8;
typedef __attribute__((ext_vector_type(4))) float f32x4;

#define MFMA16(a, b, c) __builtin_amdgcn_mfma_f32_16x16x32_bf16((a), (b), (c), 0, 0, 0)

__device__ __forceinline__ ushort f2bf(float f) {
  unsigned u = __float_as_uint(f);
  u += 0x7FFFu + ((u >> 16) & 1u);   // RNE; finite inputs
  return (ushort)(u >> 16);
}

// async 16B/lane global->LDS DMA (contiguous: LDS = uniform base + lane*16)
__device__ __forceinline__ void gl_lds16(const ushort* g, ushort* l) {
  __builtin_amdgcn_global_load_lds(
      (const __attribute__((address_space(1))) unsigned int*)g,
      (__attribute__((address_space(3))) unsigned int*)l, 16, 0, 0);
}

// ---- prologue ----
// [0,2048):    q RoPE -> qe bf16, natural [b][t][d]
// [2048,4096): k RoPE -> ktile blocked [b][it=t/32][d8][kv=t%32][8], coalesced writes
// [4096,5120): v transpose -> vtile [b][it][q4=(t%32)/8][h][8]
__global__ void prep_kernel(const float* __restrict__ q, const float* __restrict__ k,
                            const float* __restrict__ v, ushort* __restrict__ qe,
                            ushort* __restrict__ kt, ushort* __restrict__ vt) {
  __shared__ ushort tile[64][72];
  const int bid = blockIdx.x;
  const int tid = threadIdx.x;
  if (bid < 2048) {
    // q RoPE: thread = (bt, 4 consecutive j in [0,128))
    int idx = bid * 256 + tid;
    int j = (idx & 31) * 4, bt = idx >> 5;
    int t = bt & (T_ - 1);
    float cs[4], sn[4];
#pragma unroll
    for (int i = 0; i < 4; ++i) {
      float rv = (float)t * exp2f((float)(j + i) * -NFREQ) * INV2PI;
      float fr = rv - floorf(rv);
      sn[i] = __builtin_amdgcn_sinf(fr);
      cs[i] = __builtin_amdgcn_cosf(fr);
    }
    size_t base = (size_t)bt * H_ + j;
    float4 lo = *(const float4*)(q + base);
    float4 hi = *(const float4*)(q + base + 128);
    ushort4 olo, ohi;
    olo.x = f2bf(lo.x * cs[0] - hi.x * sn[0]); ohi.x = f2bf(hi.x * cs[0] + lo.x * sn[0]);
    olo.y = f2bf(lo.y * cs[1] - hi.y * sn[1]); ohi.y = f2bf(hi.y * cs[1] + lo.y * sn[1]);
    olo.z = f2bf(lo.z * cs[2] - hi.z * sn[2]); ohi.z = f2bf(hi.z * cs[2] + lo.z * sn[2]);
    olo.w = f2bf(lo.w * cs[3] - hi.w * sn[3]); ohi.w = f2bf(hi.w * cs[3] + lo.w * sn[3]);
    *(ushort4*)(qe + base) = olo; *(ushort4*)(qe + base + 128) = ohi;
  } else if (bid < 4096) {
    // k RoPE -> blocked ktile; thread = one 8-elem chunk (b,it,d8,kv); writes coalesced
    int c = (bid - 2048) * 256 + tid;
    int kv = c & 31, d8 = (c >> 5) & 31, itk = (c >> 10) & 63, b = c >> 16;
    int t = itk * 32 + kv, d0 = d8 * 8;
    const float* kr = k + ((size_t)(b * T_ + t)) * H_;
    float4 a0 = *(const float4*)(kr + d0);
    float4 a1 = *(const float4*)(kr + d0 + 4);
    int hi = d0 >= 128;
    int pd = hi ? d0 - 128 : d0 + 128;
    float4 b0 = *(const float4*)(kr + pd);
    float4 b1 = *(const float4*)(kr + pd + 4);
    int j0 = d0 & 127;
    float xs[8] = {a0.x, a0.y, a0.z, a0.w, a1.x, a1.y, a1.z, a1.w};
    float ps[8] = {b0.x, b0.y, b0.z, b0.w, b1.x, b1.y, b1.z, b1.w};
    ushort o[8];
#pragma unroll
    for (int i = 0; i < 8; ++i) {
      float rv = (float)t * exp2f((float)(j0 + i) * -NFREQ) * INV2PI;
      float fr = rv - floorf(rv);
      float sn = __builtin_amdgcn_sinf(fr), cn = __builtin_amdgcn_cosf(fr);
      o[i] = f2bf(hi ? (xs[i] * cn + ps[i] * sn) : (xs[i] * cn - ps[i] * sn));
    }
    size_t dst = ((((size_t)b * 64 + itk) * 32 + d8) * 32 + kv) * 8;
    ushort4 w0 = {o[0], o[1], o[2], o[3]}, w1 = {o[4], o[5], o[6], o[7]};
    *(ushort4*)(kt + dst) = w0;
    *(ushort4*)(kt + dst + 4) = w1;
  } else {
    // V transpose into blocked vtile, 64x64 tiles, XOR-8 swizzle in LDS
    int bid2 = bid - 4096;
    int b = bid2 >> 7, rem = bid2 & 127;
    int h0 = (rem >> 5) * 64, t0 = (rem & 31) * 64;
    int c4 = tid & 15, r0 = tid >> 4;
#pragma unroll
    for (int p = 0; p < 4; ++p) {
      int row = r0 + p * 16;
      const float4 f = *(const float4*)(v + ((size_t)(b * T_ + t0 + row)) * H_ + h0 + c4 * 4);
      ushort4 u;
      u.x = f2bf(f.x); u.y = f2bf(f.y); u.z = f2bf(f.z); u.w = f2bf(f.w);
      *(ushort4*)&tile[row][(c4 * 4) ^ (8 * ((row >> 3) & 7))] = u;
    }
    __syncthreads();
#pragma unroll
    for (int p = 0; p < 2; ++p) {
      int c = tid + p * 256;
      int h = c >> 3, tc = (c & 7) * 8;
      int xo = 8 * (c & 7);
      ushort4 u0, u1;
      u0.x = tile[tc + 0][h ^ xo]; u0.y = tile[tc + 1][h ^ xo];
      u0.z = tile[tc + 2][h ^ xo]; u0.w = tile[tc + 3][h ^ xo];
      u1.x = tile[tc + 4][h ^ xo]; u1.y = tile[tc + 5][h ^ xo];
      u1.z = tile[tc + 6][h ^ xo]; u1.w = tile[tc + 7][h ^ xo];
      int tg = t0 + tc;
      size_t dst = (((size_t)(b * 64 + (tg >> 5)) * 4 + ((tg >> 3) & 3)) * 256 + (h0 + h)) * 8;
      *(ushort4*)(vt + dst) = u0;
      *(ushort4*)(vt + dst + 4) = u1;
    }
  }
}

// ---- Flash attention, kv-split x2, K AND V ping-pong via global_load_lds:
// ONE barrier per iter (tiles DMA'd a full iteration ahead; Psh is wave-private).
__global__ __launch_bounds__(128, 1)
void attn_kernel(const ushort* __restrict__ qe, const ushort* __restrict__ kt,
                 const ushort* __restrict__ vt, float* __restrict__ out,
                 float* __restrict__ o1, float* __restrict__ lpart) {
  __shared__ ushort Ksh[2][8192];       // [buf][d8][kv32][8]  32 KB
  __shared__ ushort Vsh[2][8192];       // [buf][q4][h256][8]  32 KB
  __shared__ ushort Psh[2][32 * PSTR];  // per-wave P           5 KB   -> 69.25 KB

  const int tid = threadIdx.x;
  const int w = tid >> 6, lane = tid & 63, quad = lane >> 4, l16 = lane & 15;
  const int b = blockIdx.x;             // linear%8==b -> XCD affinity
  const int q0 = blockIdx.y * 64;
  const int sp = blockIdx.z;
  const int kvb = sp * (T_ / 2);

  // Q A-fragments (bf16, pre-roped by prep), loaded once
  bf16x8 aq[2][8];
  const ushort* qb = qe + ((size_t)(b * T_) + q0 + w * 32) * H_;
#pragma unroll
  for (int mt = 0; mt < 2; ++mt)
#pragma unroll
    for (int ks = 0; ks < 8; ++ks)
      aq[mt][ks] = *(const bf16x8*)(qb + (size_t)(mt * 16 + l16) * H_ + ks * 32 + quad * 8);

  const f32x4 fzero = {0.f, 0.f, 0.f, 0.f};
  f32x4 O[2][16], lac[2];
#pragma unroll
  for (int mt = 0; mt < 2; ++mt) {
    lac[mt] = fzero;
#pragma unroll
    for (int ht = 0; ht < 16; ++ht) O[mt][ht] = fzero;
  }
  bf16x8 vones;
#pragma unroll
  for (int i = 0; i < 8; ++i) vones[i] = (short)0x3F80;

  const ushort* ktb = kt + (size_t)(b * 64 + sp * 32) * 8192;
  const ushort* vtb = vt + (size_t)(b * 64 + sp * 32) * 8192;
  const int stoff = w * 4096 + lane * 8;   // wave-half + lane*16B

  // preload tile 0 (K then V) into buffer 0
#pragma unroll
  for (int i = 0; i < 8; ++i)
    gl_lds16(ktb + stoff + i * 512, &Ksh[0][stoff + i * 512]);
#pragma unroll
  for (int i = 0; i < 8; ++i)
    gl_lds16(vtb + stoff + i * 512, &Vsh[0][stoff + i * 512]);
  __builtin_amdgcn_sched_barrier(0);
  __builtin_amdgcn_s_waitcnt(0x0070);   // vmcnt(0) lgkm(0)
  __builtin_amdgcn_s_barrier();
  __builtin_amdgcn_sched_barrier(0);

  const float arb = SLOPE2 * (float)(q0 + w * 32 + quad * 4);

  for (int it = 0; it < 32; ++it) {
    const int p = it & 1;
    // DMA tile it+1 into the other buffer — lands during this whole iteration
    if (it < 31) {
      const ushort* kg = ktb + (size_t)(it + 1) * 8192;
      const ushort* vg = vtb + (size_t)(it + 1) * 8192;
#pragma unroll
      for (int i = 0; i < 8; ++i)
        gl_lds16(kg + stoff + i * 512, &Ksh[1 - p][stoff + i * 512]);
#pragma unroll
      for (int i = 0; i < 8; ++i)
        gl_lds16(vg + stoff + i * 512, &Vsh[1 - p][stoff + i * 512]);
    }
    __builtin_amdgcn_sched_barrier(0);

    // QK on Ksh[p]
    f32x4 s[2][2] = {{fzero, fzero}, {fzero, fzero}};
#pragma unroll
    for (int ks = 0; ks < 8; ++ks)
#pragma unroll
      for (int nt = 0; nt < 2; ++nt) {
        bf16x8 kf = *(const bf16x8*)&Ksh[p][((ks * 4 + quad) * 32 + nt * 16 + l16) * 8];
        s[0][nt] = MFMA16(aq[0][ks], kf, s[0][nt]);
        s[1][nt] = MFMA16(aq[1][ks], kf, s[1][nt]);
      }

    // p = exp2(s*SCALE2 + SLOPE2*(col-row)) -> wave-private Psh
#pragma unroll
    for (int nt = 0; nt < 2; ++nt) {
      float ac = SLOPE2 * (float)(kvb + it * 32 + nt * 16 + l16);
#pragma unroll
      for (int mt = 0; mt < 2; ++mt)
#pragma unroll
        for (int r = 0; r < 4; ++r) {
          float a0 = ac - arb - SLOPE2 * (float)(mt * 16 + r);
          float pv = __builtin_amdgcn_exp2f(fmaf(s[mt][nt][r], SCALE2, a0));
          Psh[w][(mt * 16 + quad * 4 + r) * PSTR + nt * 16 + l16] = f2bf(pv);
        }
    }

    // PV + rowsum via ones-MFMA (lgkmcnt orders wave-private P write->read)
    bf16x8 pf0 = *(const bf16x8*)&Psh[w][l16 * PSTR + quad * 8];
    bf16x8 pf1 = *(const bf16x8*)&Psh[w][(16 + l16) * PSTR + quad * 8];
    lac[0] = MFMA16(pf0, vones, lac[0]);
    lac[1] = MFMA16(pf1, vones, lac[1]);
#pragma unroll
    for (int ht = 0; ht < 16; ++ht) {
      bf16x8 vf = *(const bf16x8*)&Vsh[p][(quad * 256 + ht * 16 + l16) * 8];
      O[0][ht] = MFMA16(pf0, vf, O[0][ht]);
      O[1][ht] = MFMA16(pf1, vf, O[1][ht]);
    }

    // single barrier: next-tile DMAs (issued a full iter ago) + all LDS ops retired
    __builtin_amdgcn_sched_barrier(0);
    __builtin_amdgcn_s_waitcnt(0x0070);   // vmcnt(0) lgkm(0)
    __builtin_amdgcn_s_barrier();
    __builtin_amdgcn_sched_barrier(0);
  }

  // epilogue: unnormalized O-partial + l-partial
  float* od = (sp == 0) ? out : o1;
  float* ob = od + ((size_t)(b * T_) + q0 + w * 32) * H_;
#pragma unroll
  for (int mt = 0; mt < 2; ++mt)
#pragma unroll
    for (int r = 0; r < 4; ++r) {
      int row = mt * 16 + quad * 4 + r;
#pragma unroll
      for (int ht = 0; ht < 16; ++ht)
        ob[(size_t)row * H_ + ht * 16 + l16] = O[mt][ht][r];
    }
  if (l16 == 0) {
#pragma unroll
    for (int mt = 0; mt < 2; ++mt)
#pragma unroll
      for (int r = 0; r < 4; ++r)
        lpart[(size_t)(sp * B_ + b) * T_ + q0 + w * 32 + mt * 16 + quad * 4 + r] =
            lac[mt][r];
  }
}

// ---- combine: out = (O0 + O1) / (l0 + l1) ----
__global__ void combine_kernel(float* __restrict__ out, const float* __restrict__ o1,
                               const float* __restrict__ lpart) {
  int idx = blockIdx.x * 256 + threadIdx.x;   // over B*T*H/4
  int row = idx >> 6;
  float inv = 1.0f / (lpart[row] + lpart[B_ * T_ + row]);
  float4 a = ((const float4*)out)[idx];
  float4 c = ((const float4*)o1)[idx];
  a.x = (a.x + c.x) * inv; a.y = (a.y + c.y) * inv;
  a.z = (a.z + c.z) * inv; a.w = (a.w + c.w) * inv;
  ((float4*)out)[idx] = a;
}

extern "C" void kernel_launch(void* const* d_in, const int* in_sizes, int n_in,
                              void* d_out, int out_size, void* d_ws, size_t ws_size,
                              hipStream_t stream) {
  const float* q = (const float*)d_in[0];
  const float* k = (const float*)d_in[1];
  const float* v = (const float*)d_in[2];
  float* out = (float*)d_out;

  const size_t elems = (size_t)B_ * T_ * H_;
  ushort* qe = (ushort*)d_ws;
  ushort* kt = qe + elems;
  ushort* vt = kt + elems;
  float* o1 = (float*)(vt + elems);
  float* lpart = o1 + elems;            // 2*B*T floats

  prep_kernel<<<dim3(5120), 256, 0, stream>>>(q, k, v, qe, kt, vt);
  attn_kernel<<<dim3(B_, T_ / 64, 2), 128, 0, stream>>>(qe, kt, vt, out, o1, lpart);
  combine_kernel<<<dim3((B_ * T_ * H_ / 4) / 256), 256, 0, stream>>>(out, o1, lpart);
}